// Round 6
// baseline (90.411 us; speedup 1.0000x reference)
//
#include <hip/hip_runtime.h>
#include <math.h>

#define PI_F 3.14159265358979323846f

// ev_w(x) = sum_{t0..t3} T[w,t0..t3] * b0[t0] b1[t1] b2[t2] b3[t3],
// b_k = (1, cos x_k, sin x_k): exact multilinear form of the circuit's <Z_w>
// (verified in round 5: identical absmax to the direct simulator).
// gate_prep evaluates the direct 16-amp simulator at the 81 grid points
// {0, pi, pi/2}^4 and inverse-transforms to T (324 floats).
//
// qsim: 2 batch elements per thread; the (t0,t1) contraction loop is kept as a
// REAL 9-iteration loop (unroll disabled, pointer induction) so only 36
// coefficients are live at a time -- round 5's fully-unrolled version hoisted
// all 324 loads and spilled catastrophically.

__global__ void gate_prep(const float* __restrict__ params, float* __restrict__ g) {
    __shared__ float L[324];  // L[w*81 + i], i = ((t0*3+t1)*3+t2)*3+t3
    const int tid = threadIdx.x;

    if (tid < 81) {
        const int t3 = tid % 3, t2 = (tid / 3) % 3, t1 = (tid / 9) % 3, t0 = tid / 27;
        const float xg[3] = {0.f, PI_F, 0.5f * PI_F};
        const float xs[4] = {xg[t0], xg[t1], xg[t2], xg[t3]};

        float zr[16], zi[16];
        {
            float c[4], s[4];
            for (int k = 0; k < 4; ++k) { c[k] = cosf(0.5f * xs[k]); s[k] = sinf(0.5f * xs[k]); }
            for (int i = 0; i < 16; ++i) {
                zr[i] = ((i & 8) ? s[0] : c[0]) * ((i & 4) ? s[1] : c[1]) *
                        ((i & 2) ? s[2] : c[2]) * ((i & 1) ? s[3] : c[3]);
                zi[i] = 0.f;
            }
        }
        for (int layer = 0; layer < 2; ++layer) {
            for (int w = 0; w < 4; ++w) {
                const float p0 = params[(layer * 4 + w) * 2 + 0];  // RZ
                const float p1 = params[(layer * 4 + w) * 2 + 1];  // RX
                const float cz = cosf(0.5f * p0), sz = sinf(0.5f * p0);
                const float cx = cosf(0.5f * p1), sx = sinf(0.5f * p1);
                const float u00r = cx * cz,  u00i = -cx * sz;
                const float u01r = sx * sz,  u01i = -sx * cz;
                const float u10r = -sx * sz, u10i = -sx * cz;
                const float u11r = cx * cz,  u11i = cx * sz;
                const int M = 8 >> w;
                for (int i = 0; i < 16; ++i) {
                    if (!(i & M)) {
                        const int j = i | M;
                        const float ar = zr[i], ai = zi[i], br = zr[j], bi = zi[j];
                        zr[i] = u00r * ar - u00i * ai + u01r * br - u01i * bi;
                        zi[i] = u00r * ai + u00i * ar + u01r * bi + u01i * br;
                        zr[j] = u10r * ar - u10i * ai + u11r * br - u11i * bi;
                        zi[j] = u10r * ai + u10i * ar + u11r * bi + u11i * br;
                    }
                }
            }
            const int cm[4] = {8, 4, 2, 1}, tmm[4] = {4, 2, 1, 8};
            for (int kk = 0; kk < 4; ++kk)
                for (int i = 0; i < 16; ++i)
                    if ((i & cm[kk]) && !(i & tmm[kk])) {
                        const int j = i | tmm[kk];
                        float t;
                        t = zr[i]; zr[i] = zr[j]; zr[j] = t;
                        t = zi[i]; zi[i] = zi[j]; zi[j] = t;
                    }
        }
        float p[16];
        for (int i = 0; i < 16; ++i) p[i] = zr[i] * zr[i] + zi[i] * zi[i];
        const int wm[4] = {8, 4, 2, 1};
        for (int w = 0; w < 4; ++w) {
            float e = 0.f;
            for (int i = 0; i < 16; ++i) e += (i & wm[w]) ? -p[i] : p[i];
            L[w * 81 + tid] = e;
        }
    }
    __syncthreads();

    // Exact inverse transform per base-3 digit: v(0)=a0+a1, v(pi)=a0-a1, v(pi/2)=a0+a2.
    const int strides[4] = {27, 9, 3, 1};
    for (int d = 0; d < 4; ++d) {
        const int S = strides[d];
        if (tid < 108) {
            const int w = tid & 3, grp = tid >> 2;
            const int base = w * 81 + (grp / S) * (3 * S) + (grp % S);
            const float v0 = L[base], v1 = L[base + S], v2 = L[base + 2 * S];
            const float a0 = 0.5f * (v0 + v1);
            const float a1 = 0.5f * (v0 - v1);
            L[base] = a0;
            L[base + S] = a1;
            L[base + 2 * S] = v2 - a0;
        }
        __syncthreads();
    }

    // g[i*4 + w] = T[w, t0,t1,t2,t3]; block q=(t0*3+t1) = 36 contiguous floats.
    for (int k = tid; k < 324; k += blockDim.x) {
        g[k] = L[(k & 3) * 81 + (k >> 2)];
    }
}

__global__ __launch_bounds__(256) void qsim_kernel(const float* __restrict__ x,
                                                   const float* __restrict__ T,
                                                   float* __restrict__ out, int batch) {
    const int tid = threadIdx.x;
    const int i0 = blockIdx.x * 512 + tid;
    const int i1 = i0 + 256;

    const float4 xa = (i0 < batch) ? reinterpret_cast<const float4*>(x)[i0]
                                   : make_float4(0.f, 0.f, 0.f, 0.f);
    const float4 xb = (i1 < batch) ? reinterpret_cast<const float4*>(x)[i1]
                                   : make_float4(0.f, 0.f, 0.f, 0.f);

    float cA[4], sA[4], cB[4], sB[4];
    __sincosf(xa.x, &sA[0], &cA[0]);
    __sincosf(xa.y, &sA[1], &cA[1]);
    __sincosf(xa.z, &sA[2], &cA[2]);
    __sincosf(xa.w, &sA[3], &cA[3]);
    __sincosf(xb.x, &sB[0], &cB[0]);
    __sincosf(xb.y, &sB[1], &cB[1]);
    __sincosf(xb.z, &sB[2], &cB[2]);
    __sincosf(xb.w, &sB[3], &cB[3]);

    // u[p], p = t2*3+t3 (u[0]=1 implicit)
    float uA[9], uB[9];
    uA[1] = cA[3];          uA[2] = sA[3];
    uA[3] = cA[2];          uA[6] = sA[2];
    uA[4] = cA[2] * cA[3];  uA[5] = cA[2] * sA[3];
    uA[7] = sA[2] * cA[3];  uA[8] = sA[2] * sA[3];
    uB[1] = cB[3];          uB[2] = sB[3];
    uB[3] = cB[2];          uB[6] = sB[2];
    uB[4] = cB[2] * cB[3];  uB[5] = cB[2] * sB[3];
    uB[7] = sB[2] * cB[3];  uB[8] = sB[2] * sB[3];

    float evA[4] = {0.f, 0.f, 0.f, 0.f};
    float evB[4] = {0.f, 0.f, 0.f, 0.f};

    const float* Tp = T;
    int t0 = 0, t1 = 0;
#pragma clang loop unroll(disable)
    for (int q = 0; q < 9; ++q) {
        // 36 coefficients for this (t0,t1) block -- only these are live.
        float Tc[36];
#pragma unroll
        for (int k = 0; k < 9; ++k) {
            const float4 v = reinterpret_cast<const float4*>(Tp)[k];
            Tc[4 * k + 0] = v.x;
            Tc[4 * k + 1] = v.y;
            Tc[4 * k + 2] = v.z;
            Tc[4 * k + 3] = v.w;
        }

        float inA[4], inB[4];
#pragma unroll
        for (int w = 0; w < 4; ++w) { inA[w] = Tc[w]; inB[w] = Tc[w]; }
#pragma unroll
        for (int p = 1; p < 9; ++p)
#pragma unroll
            for (int w = 0; w < 4; ++w) {
                inA[w] = fmaf(uA[p], Tc[p * 4 + w], inA[w]);
                inB[w] = fmaf(uB[p], Tc[p * 4 + w], inB[w]);
            }

        // w_q = b0[t0] * b1[t1], selects among {1, cos, sin} (uniform t0/t1)
        const float w0A = (t0 == 0) ? 1.0f : ((t0 == 1) ? cA[0] : sA[0]);
        const float w1A = (t1 == 0) ? 1.0f : ((t1 == 1) ? cA[1] : sA[1]);
        const float w0B = (t0 == 0) ? 1.0f : ((t0 == 1) ? cB[0] : sB[0]);
        const float w1B = (t1 == 0) ? 1.0f : ((t1 == 1) ? cB[1] : sB[1]);
        const float wA = w0A * w1A;
        const float wB = w0B * w1B;

#pragma unroll
        for (int w = 0; w < 4; ++w) {
            evA[w] = fmaf(wA, inA[w], evA[w]);
            evB[w] = fmaf(wB, inB[w], evB[w]);
        }

        Tp += 36;
        if (++t1 == 3) { t1 = 0; ++t0; }
    }

    if (i0 < batch)
        reinterpret_cast<float4*>(out)[i0] = make_float4(evA[0], evA[1], evA[2], evA[3]);
    if (i1 < batch)
        reinterpret_cast<float4*>(out)[i1] = make_float4(evB[0], evB[1], evB[2], evB[3]);
}

extern "C" void kernel_launch(void* const* d_in, const int* in_sizes, int n_in,
                              void* d_out, int out_size, void* d_ws, size_t ws_size,
                              hipStream_t stream) {
    const float* x = (const float*)d_in[0];        // (B, 4) float32
    const float* params = (const float*)d_in[1];   // (2, 4, 2) float32
    float* out = (float*)d_out;                    // (B, 4) float32
    float* g = (float*)d_ws;                       // 324 floats: T tensor
    const int batch = in_sizes[0] / 4;

    gate_prep<<<1, 128, 0, stream>>>(params, g);
    const int blocks = (batch + 511) / 512;
    qsim_kernel<<<blocks, 256, 0, stream>>>(x, g, out, batch);
}

// Round 7
// 83.763 us; speedup vs baseline: 1.0794x; 1.0794x over previous
//
#include <hip/hip_runtime.h>

#define NUM_WIRES 4
#define NUM_LAYERS 2

// Direct 16-amplitude register simulator (round-4-verified math), with:
//  - all 56 batch-uniform gate constants read through an addrspace(4)
//    constant pointer -> s_load -> SGPR operands (no VMEM, no readfirstlane)
//  - 2 batch elements per thread for ILP (two independent FMA chains)
//
// ws layout (floats):
//  [ 0..15]  layer-0 per wire w: {A=cx*cz, B=cx*sz, C=sx*sz, D=sx*cz}
//  [16..23]  layer-1 RX per wire: {cos, sin}
//  [24..55]  layer-1 combined RZ diagonal: 16 x {dr, di}
//
// State layout: amp[i], bit3=wire0 ... bit0=wire3 (reference (B,2,2,2,2) order).

typedef __attribute__((address_space(4))) const float cfloat;

__global__ void gate_prep(const float* __restrict__ params, float* __restrict__ g) {
    const int t = threadIdx.x;
    if (t < 4) {
        const float p0 = params[t * 2 + 0];  // RZ
        const float p1 = params[t * 2 + 1];  // RX
        float cz, sz, cx, sx;
        __sincosf(0.5f * p0, &sz, &cz);
        __sincosf(0.5f * p1, &sx, &cx);
        g[t * 4 + 0] = cx * cz;
        g[t * 4 + 1] = cx * sz;
        g[t * 4 + 2] = sx * sz;
        g[t * 4 + 3] = sx * cz;
    } else if (t < 8) {
        const int w = t - 4;
        const float p1 = params[(NUM_WIRES + w) * 2 + 1];
        float cx, sx;
        __sincosf(0.5f * p1, &sx, &cx);
        g[16 + w * 2] = cx;
        g[17 + w * 2] = sx;
    } else if (t >= 16 && t < 32) {
        const int i = t - 16;
        float dr = 1.f, di = 0.f;
        for (int w = 0; w < NUM_WIRES; ++w) {
            const float p0 = params[(NUM_WIRES + w) * 2 + 0];
            float c, s;
            __sincosf(0.5f * p0, &s, &c);
            const float sg = ((i >> (3 - w)) & 1) ? s : -s;
            const float ndr = dr * c - di * sg;
            const float ndi = dr * sg + di * c;
            dr = ndr; di = ndi;
        }
        g[24 + i * 2] = dr;
        g[25 + i * 2] = di;
    }
}

__device__ __forceinline__ void cmul(float ar, float ai, float br, float bi,
                                     float& orr, float& oi) {
    orr = fmaf(ar, br, -(ai * bi));
    oi  = fmaf(ar, bi,   ai * br);
}

template <int CM, int TM>
__device__ __forceinline__ void cnot(float zr[16], float zi[16]) {
#pragma unroll
    for (int i = 0; i < 16; ++i) {
        if ((i & CM) && !(i & TM)) {
            const int j = i | TM;
            float t;
            t = zr[i]; zr[i] = zr[j]; zr[j] = t;
            t = zi[i]; zi[i] = zi[j]; zi[j] = t;
        }
    }
}

__device__ __forceinline__ float4 sim_one(const float4 xv, cfloat* __restrict__ G) {
    // Layer-0: fused gate applied to each wire's RY(x)|0> = (c,s) factor.
    float fr[4][2], fi[4][2];
    const float xs[4] = {xv.x, xv.y, xv.z, xv.w};
#pragma unroll
    for (int w = 0; w < 4; ++w) {
        float c, s;
        __sincosf(0.5f * xs[w], &s, &c);
        const float A = G[w * 4 + 0], B = G[w * 4 + 1];
        const float C = G[w * 4 + 2], D = G[w * 4 + 3];
        fr[w][0] = fmaf(A, c, C * s);
        fi[w][0] = fmaf(-B, c, -(D * s));
        fr[w][1] = fmaf(A, s, -(C * c));
        fi[w][1] = fmaf(B, s, -(D * c));
    }

    // Complex outer product: z = (f0 (x) f1) (x) (f2 (x) f3)
    float mr[4], mi[4], nr[4], ni[4];
#pragma unroll
    for (int p = 0; p < 2; ++p)
#pragma unroll
        for (int q = 0; q < 2; ++q) {
            cmul(fr[0][p], fi[0][p], fr[1][q], fi[1][q], mr[p * 2 + q], mi[p * 2 + q]);
            cmul(fr[2][p], fi[2][p], fr[3][q], fi[3][q], nr[p * 2 + q], ni[p * 2 + q]);
        }
    float zr[16], zi[16];
#pragma unroll
    for (int i = 0; i < 16; ++i)
        cmul(mr[i >> 2], mi[i >> 2], nr[i & 3], ni[i & 3], zr[i], zi[i]);

    // Layer-0 CNOT ring (free register permutation)
    cnot<8, 4>(zr, zi);
    cnot<4, 2>(zr, zi);
    cnot<2, 1>(zr, zi);
    cnot<1, 8>(zr, zi);

    // Layer-1 combined RZ diagonal
#pragma unroll
    for (int i = 0; i < 16; ++i) {
        const float dr = G[24 + i * 2], di = G[25 + i * 2];
        const float ar = zr[i], ai = zi[i];
        zr[i] = fmaf(dr, ar, -(di * ai));
        zi[i] = fmaf(dr, ai,   di * ar);
    }

    // Layer-1 RX per wire: new_a = c*a - i*s*b -> (c*ar + s*bi, c*ai - s*br)
#pragma unroll
    for (int w = 0; w < 4; ++w) {
        const float c = G[16 + w * 2], s = G[17 + w * 2];
        const int M = 8 >> w;
#pragma unroll
        for (int i = 0; i < 16; ++i) {
            if (!(i & M)) {
                const int j = i | M;
                const float ar = zr[i], ai = zi[i];
                const float br = zr[j], bi = zi[j];
                zr[i] = fmaf(c, ar,   s * bi);
                zi[i] = fmaf(c, ai, -(s * br));
                zr[j] = fmaf(c, br,   s * ai);
                zi[j] = fmaf(c, bi, -(s * ar));
            }
        }
    }

    // Layer-1 CNOT ring
    cnot<8, 4>(zr, zi);
    cnot<4, 2>(zr, zi);
    cnot<2, 1>(zr, zi);
    cnot<1, 8>(zr, zi);

    // Probabilities and <Z_w> via sum/difference tree
    float p[16];
#pragma unroll
    for (int i = 0; i < 16; ++i) p[i] = fmaf(zr[i], zr[i], zi[i] * zi[i]);

    float d0[8], s1[8];
#pragma unroll
    for (int k = 0; k < 8; ++k) {
        d0[k] = p[2 * k] - p[2 * k + 1];
        s1[k] = p[2 * k] + p[2 * k + 1];
    }
    const float e3 = ((d0[0] + d0[1]) + (d0[2] + d0[3])) + ((d0[4] + d0[5]) + (d0[6] + d0[7]));
    const float e2 = ((s1[0] - s1[1]) + (s1[2] - s1[3])) + ((s1[4] - s1[5]) + (s1[6] - s1[7]));
    float s2[4];
#pragma unroll
    for (int k = 0; k < 4; ++k) s2[k] = s1[2 * k] + s1[2 * k + 1];
    const float e1 = (s2[0] - s2[1]) + (s2[2] - s2[3]);
    const float e0 = (s2[0] + s2[1]) - (s2[2] + s2[3]);

    return make_float4(e0, e1, e2, e3);
}

__global__ __launch_bounds__(256) void qsim_kernel(const float* __restrict__ x,
                                                   const float* __restrict__ gf,
                                                   float* __restrict__ out, int batch) {
    cfloat* G = (cfloat*)gf;  // constant addrspace -> s_load -> SGPRs (56 floats)

    const int tid = threadIdx.x;
    const int i0 = blockIdx.x * 512 + tid;
    const int i1 = i0 + 256;

    const float4 xa = (i0 < batch) ? reinterpret_cast<const float4*>(x)[i0]
                                   : make_float4(0.f, 0.f, 0.f, 0.f);
    const float4 xb = (i1 < batch) ? reinterpret_cast<const float4*>(x)[i1]
                                   : make_float4(0.f, 0.f, 0.f, 0.f);

    const float4 ra = sim_one(xa, G);
    const float4 rb = sim_one(xb, G);

    if (i0 < batch) reinterpret_cast<float4*>(out)[i0] = ra;
    if (i1 < batch) reinterpret_cast<float4*>(out)[i1] = rb;
}

extern "C" void kernel_launch(void* const* d_in, const int* in_sizes, int n_in,
                              void* d_out, int out_size, void* d_ws, size_t ws_size,
                              hipStream_t stream) {
    const float* x = (const float*)d_in[0];        // (B, 4) float32
    const float* params = (const float*)d_in[1];   // (2, 4, 2) float32
    float* out = (float*)d_out;                    // (B, 4) float32
    float* g = (float*)d_ws;                       // 56 floats of gate constants
    const int batch = in_sizes[0] / NUM_WIRES;

    gate_prep<<<1, 64, 0, stream>>>(params, g);
    const int blocks = (batch + 511) / 512;
    qsim_kernel<<<blocks, 256, 0, stream>>>(x, g, out, batch);
}

// Round 8
// 77.959 us; speedup vs baseline: 1.1597x; 1.0744x over previous
//
#include <hip/hip_runtime.h>

#define NUM_WIRES 4
#define NUM_LAYERS 2

// Round-4 skeleton (best so far: 1 elem/thread, VGPR<=64 -> 8 waves/SIMD,
// constants via VMEM float4 + readfirstlane into SGPRs) with ONE change:
// the 4 per-thread __sincosf calls (accurate OCML sincos: ~60-100 issued
// inst each, the hidden bulk of the kernel) are replaced with native
// v_sin_f32/v_cos_f32 (input in revolutions; |x|*0.5/2pi < 0.5 for N(0,1)
// inputs, well inside the HW-accurate range).
//
// ws layout (floats):
//  [ 0..15]  layer-0 per wire w: {A=cx*cz, B=cx*sz, C=sx*sz, D=sx*cz}
//  [16..23]  layer-1 RX per wire: {cos, sin}
//  [24..55]  layer-1 combined RZ diagonal: 16 x {dr, di}
//
// State layout: amp[i], bit3=wire0 ... bit0=wire3 (reference (B,2,2,2,2) order).

#define INV_4PI 0.07957747154594767f  // 0.5 / (2*pi): sin(0.5x) = v_sin(x * INV_4PI)

__global__ void gate_prep(const float* __restrict__ params, float* __restrict__ g) {
    const int t = threadIdx.x;
    if (t < 4) {
        const float p0 = params[t * 2 + 0];  // RZ
        const float p1 = params[t * 2 + 1];  // RX
        float cz, sz, cx, sx;
        __sincosf(0.5f * p0, &sz, &cz);
        __sincosf(0.5f * p1, &sx, &cx);
        g[t * 4 + 0] = cx * cz;
        g[t * 4 + 1] = cx * sz;
        g[t * 4 + 2] = sx * sz;
        g[t * 4 + 3] = sx * cz;
    } else if (t < 8) {
        const int w = t - 4;
        const float p1 = params[(NUM_WIRES + w) * 2 + 1];
        float cx, sx;
        __sincosf(0.5f * p1, &sx, &cx);
        g[16 + w * 2] = cx;
        g[17 + w * 2] = sx;
    } else if (t >= 16 && t < 32) {
        const int i = t - 16;
        float dr = 1.f, di = 0.f;
        for (int w = 0; w < NUM_WIRES; ++w) {
            const float p0 = params[(NUM_WIRES + w) * 2 + 0];
            float c, s;
            __sincosf(0.5f * p0, &s, &c);
            const float sg = ((i >> (3 - w)) & 1) ? s : -s;
            const float ndr = dr * c - di * sg;
            const float ndi = dr * sg + di * c;
            dr = ndr; di = ndi;
        }
        g[24 + i * 2] = dr;
        g[25 + i * 2] = di;
    }
}

__device__ __forceinline__ float rfl(float v) {
    return __int_as_float(__builtin_amdgcn_readfirstlane(__float_as_int(v)));
}

__device__ __forceinline__ void cmul(float ar, float ai, float br, float bi,
                                     float& orr, float& oi) {
    orr = fmaf(ar, br, -(ai * bi));
    oi  = fmaf(ar, bi,   ai * br);
}

template <int CM, int TM>
__device__ __forceinline__ void cnot(float zr[16], float zi[16]) {
#pragma unroll
    for (int i = 0; i < 16; ++i) {
        if ((i & CM) && !(i & TM)) {
            const int j = i | TM;
            float t;
            t = zr[i]; zr[i] = zr[j]; zr[j] = t;
            t = zi[i]; zi[i] = zi[j]; zi[j] = t;
        }
    }
}

__global__ __launch_bounds__(256) void qsim_kernel(const float* __restrict__ x,
                                                   const float* __restrict__ gf,
                                                   float* __restrict__ out, int batch) {
    const int b = blockIdx.x * 256 + threadIdx.x;
    if (b >= batch) return;

    // Pull all 56 batch-uniform gate constants into SGPRs (R4-proven path).
    float G[56];
#pragma unroll
    for (int k = 0; k < 14; ++k) {
        const float4 v = reinterpret_cast<const float4*>(gf)[k];
        G[4 * k + 0] = rfl(v.x);
        G[4 * k + 1] = rfl(v.y);
        G[4 * k + 2] = rfl(v.z);
        G[4 * k + 3] = rfl(v.w);
    }

    const float4 xv = reinterpret_cast<const float4*>(x)[b];

    // Layer-0: fused gate applied to each wire's RY(x)|0> = (c,s) factor.
    // Native HW trig: sin(0.5*x) = v_sin_f32(x * INV_4PI), likewise cos.
    float fr[4][2], fi[4][2];
    {
        const float xs[4] = {xv.x, xv.y, xv.z, xv.w};
#pragma unroll
        for (int w = 0; w < 4; ++w) {
            const float r = xs[w] * INV_4PI;
            const float s = __builtin_amdgcn_sinf(r);
            const float c = __builtin_amdgcn_cosf(r);
            const float A = G[w * 4 + 0], B = G[w * 4 + 1];
            const float C = G[w * 4 + 2], D = G[w * 4 + 3];
            fr[w][0] = fmaf(A, c, C * s);      // u00r*c + u01r*s
            fi[w][0] = fmaf(-B, c, -(D * s));  // u00i*c + u01i*s
            fr[w][1] = fmaf(A, s, -(C * c));   // u10r*c + u11r*s
            fi[w][1] = fmaf(B, s, -(D * c));   // u10i*c + u11i*s
        }
    }

    // Complex outer product: z = (f0 (x) f1) (x) (f2 (x) f3)
    float mr[4], mi[4], nr[4], ni[4];
#pragma unroll
    for (int p = 0; p < 2; ++p)
#pragma unroll
        for (int q = 0; q < 2; ++q) {
            cmul(fr[0][p], fi[0][p], fr[1][q], fi[1][q], mr[p * 2 + q], mi[p * 2 + q]);
            cmul(fr[2][p], fi[2][p], fr[3][q], fi[3][q], nr[p * 2 + q], ni[p * 2 + q]);
        }
    float zr[16], zi[16];
#pragma unroll
    for (int i = 0; i < 16; ++i)
        cmul(mr[i >> 2], mi[i >> 2], nr[i & 3], ni[i & 3], zr[i], zi[i]);

    // Layer-0 CNOT ring (free register permutation)
    cnot<8, 4>(zr, zi);
    cnot<4, 2>(zr, zi);
    cnot<2, 1>(zr, zi);
    cnot<1, 8>(zr, zi);

    // Layer-1 combined RZ diagonal
#pragma unroll
    for (int i = 0; i < 16; ++i) {
        const float dr = G[24 + i * 2], di = G[25 + i * 2];
        const float ar = zr[i], ai = zi[i];
        zr[i] = fmaf(dr, ar, -(di * ai));
        zi[i] = fmaf(dr, ai,   di * ar);
    }

    // Layer-1 RX per wire: new_a = c*a - i*s*b -> (c*ar + s*bi, c*ai - s*br)
#pragma unroll
    for (int w = 0; w < 4; ++w) {
        const float c = G[16 + w * 2], s = G[17 + w * 2];
        const int M = 8 >> w;
#pragma unroll
        for (int i = 0; i < 16; ++i) {
            if (!(i & M)) {
                const int j = i | M;
                const float ar = zr[i], ai = zi[i];
                const float br = zr[j], bi = zi[j];
                zr[i] = fmaf(c, ar,   s * bi);
                zi[i] = fmaf(c, ai, -(s * br));
                zr[j] = fmaf(c, br,   s * ai);
                zi[j] = fmaf(c, bi, -(s * ar));
            }
        }
    }

    // Layer-1 CNOT ring
    cnot<8, 4>(zr, zi);
    cnot<4, 2>(zr, zi);
    cnot<2, 1>(zr, zi);
    cnot<1, 8>(zr, zi);

    // Probabilities and <Z_w> via sum/difference tree
    float p[16];
#pragma unroll
    for (int i = 0; i < 16; ++i) p[i] = fmaf(zr[i], zr[i], zi[i] * zi[i]);

    float d0[8], s1[8];
#pragma unroll
    for (int k = 0; k < 8; ++k) {
        d0[k] = p[2 * k] - p[2 * k + 1];
        s1[k] = p[2 * k] + p[2 * k + 1];
    }
    const float e3 = ((d0[0] + d0[1]) + (d0[2] + d0[3])) + ((d0[4] + d0[5]) + (d0[6] + d0[7]));
    const float e2 = ((s1[0] - s1[1]) + (s1[2] - s1[3])) + ((s1[4] - s1[5]) + (s1[6] - s1[7]));
    float s2[4];
#pragma unroll
    for (int k = 0; k < 4; ++k) s2[k] = s1[2 * k] + s1[2 * k + 1];
    const float e1 = (s2[0] - s2[1]) + (s2[2] - s2[3]);
    const float e0 = (s2[0] + s2[1]) - (s2[2] + s2[3]);

    reinterpret_cast<float4*>(out)[b] = make_float4(e0, e1, e2, e3);
}

extern "C" void kernel_launch(void* const* d_in, const int* in_sizes, int n_in,
                              void* d_out, int out_size, void* d_ws, size_t ws_size,
                              hipStream_t stream) {
    const float* x = (const float*)d_in[0];        // (B, 4) float32
    const float* params = (const float*)d_in[1];   // (2, 4, 2) float32
    float* out = (float*)d_out;                    // (B, 4) float32
    float* g = (float*)d_ws;                       // 56 floats of gate constants
    const int batch = in_sizes[0] / NUM_WIRES;

    gate_prep<<<1, 64, 0, stream>>>(params, g);
    const int blocks = (batch + 255) / 256;
    qsim_kernel<<<blocks, 256, 0, stream>>>(x, g, out, batch);
}